// Round 1
// baseline (198.272 us; speedup 1.0000x reference)
//
#include <hip/hip_runtime.h>
#include <cstdint>
#include <cstddef>

#define NN 8192
#define ATOMF 64
#define HID 128
#define HEADS 8
#define NG 256
#define ELLW 192
#define NEGSLOPE 0.2f

// ---- build ELL edge list from dense adj (one HBM pass, values held in regs) ----
__global__ __launch_bounds__(256) void k_build_ell(const float* __restrict__ adj,
                                                   int* __restrict__ ell,
                                                   int* __restrict__ deg) {
    int row = blockIdx.x;
    int t = threadIdx.x;
    const float4* a4 = (const float4*)(adj + (size_t)row * NN);
    float4 v[8];
    int c = 0;
    #pragma unroll
    for (int it = 0; it < 8; ++it) {
        v[it] = a4[it * 256 + t];
        c += (v[it].x > 0.f) + (v[it].y > 0.f) + (v[it].z > 0.f) + (v[it].w > 0.f);
    }
    __shared__ int cnt[256];
    cnt[t] = c;
    __syncthreads();
    // Hillis-Steele inclusive scan over 256 per-thread counts
    for (int off = 1; off < 256; off <<= 1) {
        int x = (t >= off) ? cnt[t - off] : 0;
        __syncthreads();
        cnt[t] += x;
        __syncthreads();
    }
    int pos = cnt[t] - c;          // exclusive prefix (deterministic order)
    int total = cnt[255];
    int* er = ell + (size_t)row * ELLW;
    #pragma unroll
    for (int it = 0; it < 8; ++it) {
        int j0 = (it * 256 + t) * 4;
        if (v[it].x > 0.f && pos < ELLW) { er[pos] = j0;     ++pos; }
        if (v[it].y > 0.f && pos < ELLW) { er[pos] = j0 + 1; ++pos; }
        if (v[it].z > 0.f && pos < ELLW) { er[pos] = j0 + 2; ++pos; }
        if (v[it].w > 0.f && pos < ELLW) { er[pos] = j0 + 3; ++pos; }
    }
    if (t == 0) deg[row] = total < ELLW ? total : ELLW;
}

// ---- reduce W[1024,128] over its 8 row-blocks -> Wr[128,128] ----
__global__ __launch_bounds__(256) void k_wreduce(const float* __restrict__ W,
                                                 float* __restrict__ Wr) {
    int i = blockIdx.x * 256 + threadIdx.x;   // 0..16383
    if (i >= HID * HID) return;
    int k = i >> 7, c = i & 127;
    float s = 0.f;
    #pragma unroll
    for (int t = 0; t < HEADS; ++t)
        s += W[(size_t)(t * HID + k) * HID + c];
    Wr[i] = s;
}

// ---- Y[N,128] = act(X[N,K]) @ W[K,128], f32 vector GEMM (tiny) ----
template<int K, bool RELU>
__global__ __launch_bounds__(256) void k_gemm(const float* __restrict__ X,
                                              const float* __restrict__ W,
                                              float* __restrict__ Y) {
    __shared__ float Xl[32 * K];
    int t = threadIdx.x;
    int row0 = blockIdx.x * 32;
    for (int i = t; i < 32 * K; i += 256) {
        int r = i / K, k = i % K;
        float x = X[(size_t)(row0 + r) * K + k];
        Xl[i] = RELU ? fmaxf(x, 0.f) : x;
    }
    __syncthreads();
    int c = t & 127;
    int rh = t >> 7;                 // 0..1 -> rows rh*16 .. rh*16+15
    float acc[16];
    #pragma unroll
    for (int m = 0; m < 16; ++m) acc[m] = 0.f;
    for (int k = 0; k < K; ++k) {
        float w = W[k * HID + c];    // coalesced, L1/L2-resident
        #pragma unroll
        for (int m = 0; m < 16; ++m)
            acc[m] += Xl[(rh * 16 + m) * K + k] * w;   // LDS broadcast
    }
    #pragma unroll
    for (int m = 0; m < 16; ++m)
        Y[(size_t)(row0 + rh * 16 + m) * HID + c] = acc[m];
}

// ---- per-row attention scores s_src[i]=h[i].a_src, s_dst[i]=h[i].a_dst ----
__global__ __launch_bounds__(256) void k_scores(const float* __restrict__ h,
                                                const float* __restrict__ asrc,
                                                const float* __restrict__ adst,
                                                float* __restrict__ ssrc,
                                                float* __restrict__ sdst) {
    int wid = threadIdx.x >> 6;
    int lane = threadIdx.x & 63;
    int row = blockIdx.x * 4 + wid;
    const float* hr = h + (size_t)row * HID;
    float h0 = hr[lane], h1 = hr[lane + 64];
    float ps = h0 * asrc[lane] + h1 * asrc[lane + 64];
    float pd = h0 * adst[lane] + h1 * adst[lane + 64];
    #pragma unroll
    for (int o = 32; o; o >>= 1) {
        ps += __shfl_xor(ps, o);
        pd += __shfl_xor(pd, o);
    }
    if (lane == 0) { ssrc[row] = ps; sdst[row] = pd; }
}

// ---- sparse masked softmax + aggregation: out[i] = sum_j attn_ij * h[j] ----
__global__ __launch_bounds__(64) void k_agg(const float* __restrict__ h,
                                            const float* __restrict__ ssrc,
                                            const float* __restrict__ sdst,
                                            const int* __restrict__ ell,
                                            const int* __restrict__ deg,
                                            float* __restrict__ out) {
    __shared__ float wl[ELLW];
    __shared__ int jl[ELLW];
    int row = blockIdx.x;
    int l = threadIdx.x;
    int d = deg[row];
    float si = ssrc[row];
    const int* er = ell + (size_t)row * ELLW;
    // phase A: e_ij = leakyrelu(src_i + dst_j), running max
    float m = -1e30f;
    for (int k = l; k < d; k += 64) {
        int j = er[k];
        float e = si + sdst[j];
        e = e > 0.f ? e : NEGSLOPE * e;
        jl[k] = j; wl[k] = e;
        m = fmaxf(m, e);
    }
    #pragma unroll
    for (int o = 32; o; o >>= 1) m = fmaxf(m, __shfl_xor(m, o));
    // phase B: w = exp(e - m), denom (each lane touches its own slots)
    float s = 0.f;
    for (int k = l; k < d; k += 64) {
        float w = __expf(wl[k] - m);
        wl[k] = w;
        s += w;
    }
    #pragma unroll
    for (int o = 32; o; o >>= 1) s += __shfl_xor(s, o);
    float inv = 1.f / s;
    __syncthreads();
    // phase C: weighted gather-sum over neighbors; lane owns dims 2l, 2l+1
    float a0 = 0.f, a1 = 0.f;
    for (int k = 0; k < d; ++k) {
        int j = jl[k];            // LDS broadcast
        float w = wl[k];          // LDS broadcast
        const float2 hv = *(const float2*)(h + (size_t)j * HID + 2 * l);
        a0 += w * hv.x; a1 += w * hv.y;
    }
    float2 o2; o2.x = a0 * inv; o2.y = a1 * inv;
    *(float2*)(out + (size_t)row * HID + 2 * l) = o2;
}

// ---- pooling: per-node dot with fc_w, segment mean, + bias ----
__global__ void k_zero(float* gsum, int* gcnt) {
    int t = blockIdx.x * 256 + threadIdx.x;
    if (t < NG) { gsum[t] = 0.f; gcnt[t] = 0; }
}

__global__ __launch_bounds__(256) void k_pool(const float* __restrict__ h,
                                              const int* __restrict__ batch,
                                              const float* __restrict__ fcw,
                                              float* __restrict__ gsum,
                                              int* __restrict__ gcnt) {
    int wid = threadIdx.x >> 6, lane = threadIdx.x & 63;
    int row = blockIdx.x * 4 + wid;
    const float* hr = h + (size_t)row * HID;
    float p = hr[lane] * fcw[lane] + hr[lane + 64] * fcw[lane + 64];
    #pragma unroll
    for (int o = 32; o; o >>= 1) p += __shfl_xor(p, o);
    if (lane == 0) {
        int g = batch[row];
        atomicAdd(&gsum[g], p);
        atomicAdd(&gcnt[g], 1);
    }
}

__global__ void k_final(const float* __restrict__ gsum, const int* __restrict__ gcnt,
                        const float* __restrict__ fcb, float* __restrict__ out) {
    int g = blockIdx.x * 256 + threadIdx.x;
    if (g < NG) out[g] = gsum[g] / fmaxf((float)gcnt[g], 1.f) + fcb[0];
}

extern "C" void kernel_launch(void* const* d_in, const int* in_sizes, int n_in,
                              void* d_out, int out_size, void* d_ws, size_t ws_size,
                              hipStream_t stream) {
    const float* x    = (const float*)d_in[0];
    const float* adj  = (const float*)d_in[1];
    const int*   batch= (const int*)  d_in[2];
    const float* W0   = (const float*)d_in[3];
    const float* a0s  = (const float*)d_in[4];
    const float* a0d  = (const float*)d_in[5];
    const float* W1   = (const float*)d_in[6];
    const float* a1s  = (const float*)d_in[7];
    const float* a1d  = (const float*)d_in[8];
    const float* W2   = (const float*)d_in[9];
    const float* a2s  = (const float*)d_in[10];
    const float* a2d  = (const float*)d_in[11];
    const float* fcw  = (const float*)d_in[12];
    const float* fcb  = (const float*)d_in[13];
    float* out = (float*)d_out;

    char* ws = (char*)d_ws;
    size_t off = 0;
    auto alloc = [&](size_t bytes) {
        char* p = ws + off;
        off = (off + bytes + 255) & ~255UL;
        return p;
    };
    int*   ell  = (int*)  alloc((size_t)NN * ELLW * 4);   // 6.3 MB
    int*   deg  = (int*)  alloc((size_t)NN * 4);
    float* hA   = (float*)alloc((size_t)NN * HID * 4);    // 4 MB
    float* hB   = (float*)alloc((size_t)NN * HID * 4);    // 4 MB
    float* ssrc = (float*)alloc((size_t)NN * 4);
    float* sdst = (float*)alloc((size_t)NN * 4);
    float* Wr1  = (float*)alloc((size_t)HID * HID * 4);
    float* Wr2  = (float*)alloc((size_t)HID * HID * 4);
    float* gsum = (float*)alloc((size_t)NG * 4);
    int*   gcnt = (int*)  alloc((size_t)NG * 4);
    (void)ws_size; (void)in_sizes; (void)n_in; (void)out_size;

    k_build_ell<<<NN, 256, 0, stream>>>(adj, ell, deg);
    k_wreduce<<<64, 256, 0, stream>>>(W1, Wr1);
    k_wreduce<<<64, 256, 0, stream>>>(W2, Wr2);

    // layer 0
    k_gemm<ATOMF, false><<<NN / 32, 256, 0, stream>>>(x, W0, hA);
    k_scores<<<NN / 4, 256, 0, stream>>>(hA, a0s, a0d, ssrc, sdst);
    k_agg<<<NN, 64, 0, stream>>>(hA, ssrc, sdst, ell, deg, hB);
    // layer 1 (tile+relu collapses to relu(h) @ Wr1)
    k_gemm<HID, true><<<NN / 32, 256, 0, stream>>>(hB, Wr1, hA);
    k_scores<<<NN / 4, 256, 0, stream>>>(hA, a1s, a1d, ssrc, sdst);
    k_agg<<<NN, 64, 0, stream>>>(hA, ssrc, sdst, ell, deg, hB);
    // layer 2
    k_gemm<HID, true><<<NN / 32, 256, 0, stream>>>(hB, Wr2, hA);
    k_scores<<<NN / 4, 256, 0, stream>>>(hA, a2s, a2d, ssrc, sdst);
    k_agg<<<NN, 64, 0, stream>>>(hA, ssrc, sdst, ell, deg, hB);

    // global mean pool (linear => pool scalar dots) + fc
    k_zero<<<1, 256, 0, stream>>>(gsum, gcnt);
    k_pool<<<NN / 4, 256, 0, stream>>>(hB, batch, fcw, gsum, gcnt);
    k_final<<<1, 256, 0, stream>>>(gsum, gcnt, fcb, out);
}